// Round 9
// baseline (770.984 us; speedup 1.0000x reference)
//
#include <hip/hip_runtime.h>
#include <math.h>

#define T_STEPS 8
#define HW 4096
#define XSTR 192                    // XT channel stride (fixed, max cin)
#define FR_ROW 4352                 // convx u16 per (img,row)

typedef unsigned short u16;
typedef __attribute__((ext_vector_type(8))) short short8;
typedef __attribute__((ext_vector_type(4))) short short4v;
typedef __attribute__((ext_vector_type(4))) float f32x4;

__device__ __forceinline__ u16 f2bf(float f) {
    unsigned u = __builtin_bit_cast(unsigned, f);
    u += 0x7fffu + ((u >> 16) & 1u);
    return (u16)(u >> 16);
}
__device__ __forceinline__ float bf2f(u16 h) {
    unsigned u = ((unsigned)h) << 16;
    return __builtin_bit_cast(float, u);
}
__device__ __forceinline__ float ftanh(float x) {
    float e = __expf(2.f * x);
    return 1.f - 2.f * __builtin_amdgcn_rcpf(e + 1.f);
}
__device__ __forceinline__ float fsigm(float x) {
    return __builtin_amdgcn_rcpf(1.f + __expf(-x));
}

// ---------------------------------------------------------------------------
// l0 only: fp32 x [img][32][64][64] -> bf16 XT[img][66][66][192] ch 0..31
// ---------------------------------------------------------------------------
__global__ __launch_bounds__(256) void transpose_halo(
    const float* __restrict__ src, u16* __restrict__ XT, int src_ctot)
{
    __shared__ float tile[32][257];
    const int img = blockIdx.z;
    const int px0 = blockIdx.x * 256;
    const float* s = src + (size_t)img * src_ctot * HW + px0;
    #pragma unroll
    for (int c = 0; c < 32; ++c)
        tile[c][threadIdx.x] = s[(size_t)c * HW + threadIdx.x];
    __syncthreads();
    const int c = threadIdx.x & 31, pb = threadIdx.x >> 5;
    const int r0 = px0 >> 6;
    for (int p = pb; p < 256; p += 8) {
        int row = r0 + (p >> 6), col = p & 63;
        XT[((size_t)img * 4356 + (row + 1) * 66 + col + 1) * XSTR + c] = f2bf(tile[c][p]);
    }
}

// ---------------------------------------------------------------------------
// Pack ALL layers' weights in one launch:
// Wr[l] at offs[l], layout [dir][tap][80][ci_total(l)] bf16 (co >= 65 zeroed)
// ---------------------------------------------------------------------------
struct WP { const float* p[8]; };   // wf0,wb0,wf1,wb1,wf2,wb2,wf3,wb3

__global__ __launch_bounds__(256) void prep_w_all(WP wp, u16* __restrict__ Wr)
{
    int idx = blockIdx.x * 256 + threadIdx.x;
    if (idx >= 783360) return;
    const int offs[5] = {0, 92160, 230400, 460800, 783360};
    const int cit[4]  = {64, 96, 160, 224};
    int lay = 0;
    while (idx >= offs[lay + 1]) ++lay;
    int li = idx - offs[lay];
    int ci_total = cit[lay];
    int ci = li % ci_total;
    int rest = li / ci_total;
    int co = rest % 80; rest /= 80;
    int tap = rest % 9;
    int dir = rest / 9;
    const float* w = wp.p[lay * 2 + dir];
    float v = (co < 65) ? w[((size_t)co * ci_total + ci) * 9 + tap] : 0.f;
    Wr[idx] = f2bf(v);
}

// ---------------------------------------------------------------------------
// MFMA x-conv (r6 version): dir-fused, single 25KB LDS stage.
// 8 waves = 4 rows x 2 dirs share the stage; reuse across 9 taps x 8 waves.
// ---------------------------------------------------------------------------
__global__ __launch_bounds__(512, 2) void convx_mfma(
    const u16* __restrict__ XT, const u16* __restrict__ Wr,
    const float* __restrict__ b_f, const float* __restrict__ b_b,
    u16* __restrict__ convx, int cin, int ci_total)
{
    __shared__ u16 xs[6 * 66 * 32];       // 25,344 B
    const int tid = threadIdx.x;
    const int l = tid & 63, wv = tid >> 6;   // 8 waves
    const int g = l >> 4, ln16 = l & 15;
    const int img = blockIdx.z;              // t*4 + b
    const int dir = wv & 1;
    const int wrow = wv >> 1;                // 0..3
    const int r0  = blockIdx.x * 4;
    const int orow = r0 + wrow;

    const float* bias = dir ? b_b : b_f;
    f32x4 acc[5][4];
    #pragma unroll
    for (int mt = 0; mt < 5; ++mt)
        #pragma unroll
        for (int r = 0; r < 4; ++r) {
            int co = mt * 16 + g * 4 + r;
            float bv = (co < 65) ? bias[co] : 0.f;
            #pragma unroll
            for (int nt = 0; nt < 4; ++nt) acc[mt][nt][r] = bv;
        }

    const u16* wdir = Wr + (size_t)dir * 9 * 80 * ci_total + g * 8;
    const u16* xim  = XT + (size_t)img * 4356 * XSTR;

    for (int ch = 0; ch < cin; ch += 32) {
        __syncthreads();
        // stage rows r0..r0+5, 66 px, 32 ch -> 1584 x 16B across 512 threads
        #pragma unroll
        for (int k = 0; k < 4; ++k) {
            int idx = k * 512 + tid;
            if (idx < 1584) {
                int seg = idx & 3;
                int pr  = idx >> 2;
                short8 v = *(const short8*)(xim + (size_t)(r0 * 66 + pr) * XSTR + ch + seg * 8);
                *(short8*)(xs + (size_t)idx * 8) = v;
            }
        }
        __syncthreads();

        #pragma unroll
        for (int ky = 0; ky < 3; ++ky) {
            #pragma unroll
            for (int kx = 0; kx < 3; ++kx) {
                const int tap = ky * 3 + kx;
                const u16* xb = xs + ((size_t)((wrow + ky) * 66 + ln16 + kx)) * 32 + g * 8;
                short8 bv0 = *(const short8*)(xb);
                short8 bv1 = *(const short8*)(xb + 16 * 32);
                short8 bv2 = *(const short8*)(xb + 32 * 32);
                short8 bv3 = *(const short8*)(xb + 48 * 32);
                const u16* wb_ = wdir + ((size_t)tap * 80 + ln16) * ci_total + ch;
                #pragma unroll
                for (int mt = 0; mt < 5; ++mt) {
                    short8 af = *(const short8*)(wb_ + (size_t)mt * 16 * ci_total);
                    acc[mt][0] = __builtin_amdgcn_mfma_f32_16x16x32_bf16(af, bv0, acc[mt][0], 0, 0, 0);
                    acc[mt][1] = __builtin_amdgcn_mfma_f32_16x16x32_bf16(af, bv1, acc[mt][1], 0, 0, 0);
                    acc[mt][2] = __builtin_amdgcn_mfma_f32_16x16x32_bf16(af, bv2, acc[mt][2], 0, 0, 0);
                    acc[mt][3] = __builtin_amdgcn_mfma_f32_16x16x32_bf16(af, bv3, acc[mt][3], 0, 0, 0);
                }
            }
        }
    }

    const int zimg = dir * 32 + img;
    u16* cb = convx + ((size_t)zimg * 64 + orow) * FR_ROW;
    #pragma unroll
    for (int mt = 0; mt < 4; ++mt)
        #pragma unroll
        for (int nt = 0; nt < 4; ++nt) {
            short4v pk;
            #pragma unroll
            for (int r = 0; r < 4; ++r) pk[r] = (short)f2bf(acc[mt][nt][r]);
            *(short4v*)(cb + (size_t)(nt * 4 + mt) * 256 + l * 4) = pk;
        }
    if (g == 0) {
        #pragma unroll
        for (int nt = 0; nt < 4; ++nt) {
            short4v pk;
            #pragma unroll
            for (int r = 0; r < 4; ++r) pk[r] = (short)f2bf(acc[4][nt][r]);
            *(short4v*)(cb + 4096 + nt * 64 + ln16 * 4) = pk;
        }
    }
}

// ---------------------------------------------------------------------------
// Fully-fused recurrent kernel: ALL 8 steps in one launch, NO inter-block
// sync. Trapezoid scheme: block owns 2 rows (rb); phase p computes rows
// r0-(7-p) .. r0+1+(7-p); c state lives ONLY in LDS (ping-pong, 16-row
// window rows r0-7..r0+8). Phase 0 skips the c-conv (c=0). Redundant rows
// are computed but only owned rows write globals. bid = rb*8+z pins z to
// one XCD (convx L2 locality) and keeps row-neighbors XCD-local.
// ---------------------------------------------------------------------------
__global__ __launch_bounds__(512, 2) void rec8_mfma(
    const u16* __restrict__ Wr, const u16* __restrict__ convx,
    float* __restrict__ out_t, float* __restrict__ lrh,
    float* __restrict__ lrc, float* __restrict__ lrg,
    u16* __restrict__ XT, int cin, int ci_total, int layer)
{
    __shared__ u16 cls[2][4 * 16 * 66 * 8];   // 2 x 67,584 B = 135,168 B
    const int tid = threadIdx.x;
    const int l = tid & 63, w = tid >> 6;     // 8 waves
    const int g = l >> 4, ln16 = l & 15;
    const int bid = blockIdx.x;
    const int rb = bid >> 3, z = bid & 7;     // z = dir*4 + b
    const int dir = z >> 2, b = z & 3;
    const int r0 = rb * 2;

    {   // zero both c buffers (out-of-image rows + halo cols stay 0 forever)
        short8 zz = {0, 0, 0, 0, 0, 0, 0, 0};
        short8* f = (short8*)&cls[0][0];
        for (int i = tid; i < 8448; i += 512) f[i] = zz;
    }
    __syncthreads();

    const u16* wdir = Wr + (size_t)dir * 9 * 80 * ci_total + cin + g * 8;

    #pragma unroll 1
    for (int p = 0; p < 8; ++p) {
        u16* wlds        = cls[p & 1];
        const u16* rlds  = cls[(p & 1) ^ 1];
        const int t = dir ? (7 - p) : p;
        const int zimg = dir * 32 + t * 4 + b;
        const int rlo = r0 - 7 + p;
        const int ntasks = (16 - 2 * p) * 2;
        const bool last_f = (dir == 0) && (p == 7);

        #pragma unroll 1
        for (int task = w; task < ntasks; task += 8) {
            const int rowA = rlo + (task >> 1);
            if ((unsigned)rowA >= 64u) continue;
            const int nb2 = (task & 1) * 2;
            const int col0 = nb2 * 16;

            // init acc from convx fragments
            const u16* cxb = convx + ((size_t)zimg * 64 + rowA) * FR_ROW;
            f32x4 acc[5][2];
            #pragma unroll
            for (int mt = 0; mt < 4; ++mt)
                #pragma unroll
                for (int nt = 0; nt < 2; ++nt) {
                    short4v pk = *(const short4v*)(cxb + (size_t)((nb2 + nt) * 4 + mt) * 256 + l * 4);
                    #pragma unroll
                    for (int r = 0; r < 4; ++r) acc[mt][nt][r] = bf2f((u16)pk[r]);
                }
            #pragma unroll
            for (int nt = 0; nt < 2; ++nt) {
                if (g == 0) {
                    short4v pk = *(const short4v*)(cxb + 4096 + (nb2 + nt) * 64 + ln16 * 4);
                    #pragma unroll
                    for (int r = 0; r < 4; ++r) acc[4][nt][r] = bf2f((u16)pk[r]);
                } else {
                    #pragma unroll
                    for (int r = 0; r < 4; ++r) acc[4][nt][r] = 0.f;
                }
            }

            // conv over c_{p-1} from LDS (phase 0: c = 0, skip)
            if (p > 0) {
                #pragma unroll
                for (int ky = 0; ky < 3; ++ky) {
                    #pragma unroll
                    for (int kx = 0; kx < 3; ++kx) {
                        const int tap = ky * 3 + kx;
                        const int lr = rowA - r0 + 6 + ky;       // in [0,15]
                        const int colv = col0 + ln16 + kx;
                        const u16* xb_ = rlds + ((size_t)((g * 16 + lr) * 66 + colv)) * 8;
                        short8 bv0 = *(const short8*)(xb_);
                        short8 bv1 = *(const short8*)(xb_ + 128);   // col+16
                        #pragma unroll
                        for (int mt = 0; mt < 5; ++mt) {
                            short8 af = *(const short8*)(wdir + ((size_t)tap * 80 + ln16) * ci_total
                                                         + (size_t)mt * 16 * ci_total);
                            acc[mt][0] = __builtin_amdgcn_mfma_f32_16x16x32_bf16(af, bv0, acc[mt][0], 0, 0, 0);
                            acc[mt][1] = __builtin_amdgcn_mfma_f32_16x16x32_bf16(af, bv1, acc[mt][1], 0, 0, 0);
                        }
                    }
                }
            }

            float val[2], gv[2];
            #pragma unroll
            for (int nt = 0; nt < 2; ++nt) {
                val[nt] = fsigm(ftanh(acc[4][nt][0]));
                gv[nt]  = __shfl(val[nt], ln16);     // broadcast from g==0 lanes
            }

            const bool owned = (rowA >= r0) && (rowA < r0 + 2);
            if (owned) {
                const size_t obase = (size_t)(t * 4 + b) * 256 + 64 * layer + dir * 32;
                const int chb = 64 * layer + dir * 32;
                #pragma unroll
                for (int mt = 0; mt < 2; ++mt)
                    #pragma unroll
                    for (int nt = 0; nt < 2; ++nt) {
                        int px = rowA * 64 + col0 + nt * 16 + ln16;
                        short4v pkh;
                        #pragma unroll
                        for (int r = 0; r < 4; ++r) {
                            int co = mt * 16 + g * 4 + r;
                            float v = ftanh(acc[mt][nt][r]);
                            out_t[(obase + co) * HW + px] = v;
                            pkh[r] = (short)f2bf(v);
                            if (last_f) lrh[((size_t)(layer * 4 + b) * 32 + co) * HW + px] = v;
                        }
                        if (layer < 3)
                            *(short4v*)(XT + ((size_t)(t * 4 + b) * 4356 + (rowA + 1) * 66 +
                                              (col0 + nt * 16 + ln16 + 1)) * XSTR + chb + mt * 16 + g * 4) = pkh;
                    }
                if (last_f && g == 0) {
                    #pragma unroll
                    for (int nt = 0; nt < 2; ++nt)
                        lrg[(size_t)(layer * 4 + b) * HW + rowA * 64 + col0 + nt * 16 + ln16] = val[nt];
                }
            }

            // c_p -> LDS write buffer (all computed rows, incl. redundant)
            const int lrW = rowA - r0 + 7;                        // in [0,15]
            #pragma unroll
            for (int mt = 2; mt < 4; ++mt)
                #pragma unroll
                for (int nt = 0; nt < 2; ++nt) {
                    short4v pk;
                    #pragma unroll
                    for (int r = 0; r < 4; ++r) {
                        int k = (mt - 2) * 16 + g * 4 + r;
                        float cval = gv[nt] * ftanh(acc[mt][nt][r]);
                        pk[r] = (short)f2bf(cval);
                        if (last_f && owned)
                            lrc[((size_t)(layer * 4 + b) * 32 + k) * HW + rowA * 64 + col0 + nt * 16 + ln16] = cval;
                    }
                    int colh = col0 + nt * 16 + ln16 + 1;
                    int J = (mt - 2) * 2 + (g >> 1);
                    *(short4v*)(wlds + ((size_t)((J * 16 + lrW) * 66 + colh)) * 8 + (g & 1) * 4) = pk;
                }
        }
        __syncthreads();
    }
}

extern "C" void kernel_launch(void* const* d_in, const int* in_sizes, int n_in,
                              void* d_out, int out_size, void* d_ws, size_t ws_size,
                              hipStream_t stream)
{
    const float* x = (const float*)d_in[0];
    float* out = (float*)d_out;                       // (8,4,256,64,64)
    float* lrh = out + (size_t)33554432;
    float* lrc = lrh + (size_t)2097152;
    float* lrg = lrc + (size_t)2097152;

    char* ws = (char*)d_ws;
    u16* convx = (u16*)ws;                            // 35,651,584 B
    size_t off = 35651584 + 4096;
    u16* XT = (u16*)(ws + off); off += 53526528;      // 32*4356*192*2
    u16* Wr = (u16*)(ws + off);                       // 783360*2 B (all layers)

    static const int offs[4] = {0, 92160, 230400, 460800};

    hipMemsetAsync(XT, 0, 53526528, stream);
    transpose_halo<<<dim3(16, 1, 32), 256, 0, stream>>>(x, XT, 32);

    WP wp;
    for (int l = 0; l < 4; ++l) {
        wp.p[l * 2]     = (const float*)d_in[1 + 4 * l];
        wp.p[l * 2 + 1] = (const float*)d_in[3 + 4 * l];
    }
    prep_w_all<<<dim3((783360 + 255) / 256), 256, 0, stream>>>(wp, Wr);

    for (int l = 0; l < 4; ++l) {
        const float* bf = (const float*)d_in[2 + 4 * l];
        const float* bb = (const float*)d_in[4 + 4 * l];
        int cin = (l == 0) ? 32 : 64 * l;
        int ci_total = cin + 32;
        const u16* Wrl = Wr + offs[l];

        convx_mfma<<<dim3(16, 1, 32), 512, 0, stream>>>(XT, Wrl, bf, bb, convx, cin, ci_total);
        rec8_mfma<<<dim3(256), 512, 0, stream>>>(
            Wrl, convx, out, lrh, lrc, lrg, XT, cin, ci_total, l);
    }
}